// Round 6
// baseline (86.556 us; speedup 1.0000x reference)
//
#include <hip/hip_runtime.h>
#include <stdint.h>

typedef unsigned int u32;
typedef unsigned short u16;
typedef short short8 __attribute__((ext_vector_type(8)));
typedef float f32x16 __attribute__((ext_vector_type(16)));

#define BN 8192
#define NPB 128           // partial blocks per batch (1 tile of 64 rows each)

__device__ __forceinline__ u32 f2b_u(float f){
  u32 x = __float_as_uint(f);
  return (x + 0x7fffu + ((x >> 16) & 1u)) >> 16;   // RNE f32->bf16
}
__device__ __forceinline__ float gelu_exact(float v){
  return 0.5f * v * (1.0f + erff(v * 0.70710678118654752440f));
}

// ---------------------------------------------------------------------------
// K1: per-block partial Gram via MFMA. One 64-row tile per block.
// grid = 4*NPB = 512 blocks (2/CU), 256 threads, single barrier.
// partial layout per block: 4096 floats G[i][j] + 64 floats m[j].
// ---------------------------------------------------------------------------
__global__ __launch_bounds__(256) void k_gram(const float* __restrict__ x,
                                              float* __restrict__ part){
  int bid = blockIdx.x;
  int b = bid >> 7, blk = bid & (NPB - 1);
  int t = threadIdx.x, w = t >> 6, lane = t & 63;
  const float* xb = x + (size_t)b * BN * 64 + (size_t)blk * 64 * 64;

  __shared__ __align__(16) u16 xT[64][72];     // [col][row] bf16, pad 72
  __shared__ float mred[256][16];

  int wi = w >> 1, wj = w & 1;                 // wave's G quadrant
  int r = t >> 2, cg = t & 3;                  // staging: row r, col-group cg

  // ---- stage 64 rows transposed bf16 + per-thread m partials ----
  const float4* src = (const float4*)(xb + (size_t)r * 64 + cg * 16);
  float4 v0 = src[0], v1 = src[1], v2 = src[2], v3 = src[3];
  float vv[16] = { v0.x, v0.y, v0.z, v0.w,  v1.x, v1.y, v1.z, v1.w,
                   v2.x, v2.y, v2.z, v2.w,  v3.x, v3.y, v3.z, v3.w };
  #pragma unroll
  for (int j = 0; j < 16; ++j){
    mred[t][j] = vv[j];
    xT[cg * 16 + j][r] = (u16)f2b_u(vv[j]);
  }
  __syncthreads();

  // ---- MFMA: 4 K-steps of 16 ----
  f32x16 acc;
  #pragma unroll
  for (int i = 0; i < 16; ++i) acc[i] = 0.f;
  #pragma unroll
  for (int ks = 0; ks < 4; ++ks){
    int n0 = ks * 16 + (lane >> 5) * 8;
    short8 af = *(const short8*)&xT[wi * 32 + (lane & 31)][n0];
    short8 bf = *(const short8*)&xT[wj * 32 + (lane & 31)][n0];
    acc = __builtin_amdgcn_mfma_f32_32x32x16_bf16(af, bf, acc, 0, 0, 0);
  }

  // ---- write G partial: C/D map col=lane&31, row=(reg&3)+8*(reg>>2)+4*(lane>>5)
  float* dst = part + (size_t)bid * 4160;
  #pragma unroll
  for (int rr = 0; rr < 16; ++rr){
    int grow = wi * 32 + (rr & 3) + 8 * (rr >> 2) + 4 * (lane >> 5);
    int gcol = wj * 32 + (lane & 31);
    dst[grow * 64 + gcol] = acc[rr];
  }

  // ---- m border: sum mred over the 64 rows (threads with same cg) ----
  if (t < 64){
    int cgc = t >> 4, j = t & 15;
    float s0 = 0.f, s1 = 0.f, s2 = 0.f, s3 = 0.f;
    for (int ss = 0; ss < 64; ss += 4){
      s0 += mred[cgc + 4 * ss][j];
      s1 += mred[cgc + 4 * (ss + 1)][j];
      s2 += mred[cgc + 4 * (ss + 2)][j];
      s3 += mred[cgc + 4 * (ss + 3)][j];
    }
    dst[4096 + t] = (s0 + s1) + (s2 + s3);
  }
}

// ---------------------------------------------------------------------------
// K2: parallel reduction of partials -> Gred[4][4160]. grid = 65 blocks.
// ---------------------------------------------------------------------------
__global__ __launch_bounds__(256) void k_reduce(const float* __restrict__ part,
                                                float* __restrict__ Gred){
  int gid = blockIdx.x * 256 + threadIdx.x;   // exactly 65*256 = 16640
  int b = gid / 4160, idx = gid - b * 4160;
  const float* pb = part + (size_t)b * NPB * 4160 + idx;
  float s0 = 0.f, s1 = 0.f, s2 = 0.f, s3 = 0.f;
  #pragma unroll 4
  for (int p = 0; p < NPB; p += 4){
    s0 += pb[(size_t)p * 4160];
    s1 += pb[(size_t)(p + 1) * 4160];
    s2 += pb[(size_t)(p + 2) * 4160];
    s3 += pb[(size_t)(p + 3) * 4160];
  }
  Gred[gid] = (s0 + s1) + (s2 + s3);
}

// ---------------------------------------------------------------------------
// K3: per-batch combine. grid = 4 blocks, 256 threads. 4-way split
// accumulators to shorten the serial fma chains (latency-bound kernel).
//   T  = W~k G~          (64 x 65)
//   S  = T W~v^T         (64 x 64) stored transposed: St[j][i] = S[i][j]
//   M~ = W~w + INV8N * (S contracted with W~q)  (64 x 65, col 64 = const)
// ---------------------------------------------------------------------------
__global__ __launch_bounds__(256) void k_combine(
    const float* __restrict__ Gred,
    const float* __restrict__ Wq, const float* __restrict__ bq,
    const float* __restrict__ Wk, const float* __restrict__ bk,
    const float* __restrict__ Wv, const float* __restrict__ bv,
    const float* __restrict__ Ww, const float* __restrict__ bw,
    float* __restrict__ Mt){
  int b = blockIdx.x;
  int t = threadIdx.x, w = t >> 6, lane = t & 63;

  __shared__ __align__(16) float Gt[65 * 68];
  __shared__ __align__(16) float Tl[64 * 68];
  __shared__ __align__(16) float St[64 * 68];

  const float* Gb = Gred + (size_t)b * 4160;
  for (int idx = t; idx < 4096; idx += 256)
    Gt[(idx >> 6) * 68 + (idx & 63)] = Gb[idx];
  if (t < 64){ float m = Gb[4096 + t]; Gt[64 * 68 + t] = m; Gt[t * 68 + 64] = m; }
  if (t == 0) Gt[64 * 68 + 64] = (float)BN;
  __syncthreads();

  // ---- T[i][c] = sum_a W~k[i][a] G~[a][c], c = lane ----
  {
    float gcol[65];
    #pragma unroll
    for (int a = 0; a < 65; ++a) gcol[a] = Gt[a * 68 + lane];
    for (int i = w * 16; i < w * 16 + 16; ++i){
      float s0 = 0.f, s1 = 0.f, s2 = 0.f, s3 = 0.f;
      #pragma unroll
      for (int a = 0; a < 64; a += 4){
        s0 = fmaf(Wk[i * 64 + a],     gcol[a],     s0);
        s1 = fmaf(Wk[i * 64 + a + 1], gcol[a + 1], s1);
        s2 = fmaf(Wk[i * 64 + a + 2], gcol[a + 2], s2);
        s3 = fmaf(Wk[i * 64 + a + 3], gcol[a + 3], s3);
      }
      Tl[i * 68 + lane] = ((s0 + s1) + (s2 + s3)) + bk[i] * gcol[64];
    }
  }
  if (w == 0){   // column 64 of T, lane = i
    float s = 0.f;
    for (int a = 0; a < 64; ++a) s = fmaf(Wk[lane * 64 + a], Gt[a * 68 + 64], s);
    s = fmaf(bk[lane], (float)BN, s);
    Tl[lane * 68 + 64] = s;
  }
  __syncthreads();

  // ---- St[j][i] = S[i][j] = sum_c T[i][c] W~v[j][c], j = lane ----
  {
    float wv[65];
    const float4* Wv4 = (const float4*)(Wv + (size_t)lane * 64);
    #pragma unroll
    for (int c4 = 0; c4 < 16; ++c4){
      float4 vv = Wv4[c4];
      wv[4*c4] = vv.x; wv[4*c4+1] = vv.y; wv[4*c4+2] = vv.z; wv[4*c4+3] = vv.w;
    }
    wv[64] = bv[lane];
    for (int i = w * 16; i < w * 16 + 16; ++i){
      const float4* Tr = (const float4*)&Tl[i * 68];
      float s0 = 0.f, s1 = 0.f, s2 = 0.f, s3 = 0.f;
      #pragma unroll
      for (int cc = 0; cc < 16; ++cc){
        float4 tv = Tr[cc];
        s0 = fmaf(tv.x, wv[4*cc],     s0);
        s1 = fmaf(tv.y, wv[4*cc + 1], s1);
        s2 = fmaf(tv.z, wv[4*cc + 2], s2);
        s3 = fmaf(tv.w, wv[4*cc + 3], s3);
      }
      St[lane * 68 + i] = ((s0 + s1) + (s2 + s3)) + Tl[i * 68 + 64] * wv[64];
    }
  }
  __syncthreads();

  // ---- M~[d][c] = W~w[d][c] + INV8N * sum_e S[e][d] W~q[e][c] ----
  {
    const float inv = 1.0f / 65536.0f;   // 1/(sqrt(64)*8192)
    float wq[64];
    #pragma unroll
    for (int i = 0; i < 64; ++i) wq[i] = Wq[i * 64 + lane];   // column c = lane
    float* Mb = Mt + (size_t)b * 4160;
    for (int d = w * 16; d < w * 16 + 16; ++d){
      const float4* Sr = (const float4*)&St[d * 68];
      float s0 = 0.f, s1 = 0.f, s2 = 0.f, s3 = 0.f;
      #pragma unroll
      for (int ii = 0; ii < 16; ++ii){
        float4 sv = Sr[ii];
        s0 = fmaf(sv.x, wq[4*ii],     s0);
        s1 = fmaf(sv.y, wq[4*ii + 1], s1);
        s2 = fmaf(sv.z, wq[4*ii + 2], s2);
        s3 = fmaf(sv.w, wq[4*ii + 3], s3);
      }
      Mb[d * 65 + lane] = fmaf(inv, (s0 + s1) + (s2 + s3), Ww[d * 64 + lane]);
    }
    if (w == 0){   // affine-const column, lane = d
      float s = 0.f;
      for (int i = 0; i < 64; ++i) s = fmaf(St[lane * 68 + i], bq[i], s);
      Mb[lane * 65 + 64] = fmaf(inv, s, bw[lane]);
    }
  }
}

// ---------------------------------------------------------------------------
// K4: out_n = gelu(M~ x~_n), FP32 out. grid = 256 blocks (64/batch).
// Wave w: h=w&1 row-half (lane = row), dh=w>>1 channel-half (32 ch).
// LDS float2 transpose -> coalesced 128B row-segment stores.
// ---------------------------------------------------------------------------
__global__ __launch_bounds__(256) void k_out(const float* __restrict__ x,
                                             const float* __restrict__ Mt,
                                             float* __restrict__ out){
  int bid = blockIdx.x;
  int b = bid >> 6, blk = bid & 63;
  int t = threadIdx.x, w = t >> 6, lane = t & 63;
  int h = w & 1, dh = w >> 1;
  int r0 = blk * 128 + h * 64;
  int row = r0 + lane;

  const float4* xr4 = (const float4*)(x + ((size_t)(b * BN + row)) * 64);
  float xv[64];
  #pragma unroll
  for (int q = 0; q < 16; ++q){
    float4 u = xr4[q];
    xv[4*q] = u.x; xv[4*q+1] = u.y; xv[4*q+2] = u.z; xv[4*q+3] = u.w;
  }

  __shared__ __align__(16) float tp[4][64 * 34];
  float* tpw = &tp[w][0];
  const float* Mb = Mt + (size_t)b * 4160;

  #pragma unroll 1
  for (int dd = 0; dd < 16; ++dd){
    int d0 = dh * 32 + 2 * dd, d1 = d0 + 1;
    float a0 = Mb[d0 * 65 + 64];      // affine const (uniform -> s_load)
    float a1 = Mb[d1 * 65 + 64];
    #pragma unroll
    for (int c = 0; c < 64; ++c){
      a0 = fmaf(Mb[d0 * 65 + c], xv[c], a0);
      a1 = fmaf(Mb[d1 * 65 + c], xv[c], a1);
    }
    a0 = gelu_exact(a0);
    a1 = gelu_exact(a1);
    *(float2*)&tpw[lane * 34 + 2 * dd] = make_float2(a0, a1);
  }
  __syncthreads();

  // store: 4 rows per iter, 16 lanes cover one 32-float (128B) row segment
  #pragma unroll 1
  for (int rr = 0; rr < 16; ++rr){
    int rloc = rr * 4 + (lane >> 4);
    int p = lane & 15;
    float2 v = *(const float2*)&tpw[rloc * 34 + 2 * p];
    float* dst = out + ((size_t)(b * BN + r0 + rloc)) * 64 + dh * 32 + 2 * p;
    *(float2*)dst = v;
  }
}

// ---------------------------------------------------------------------------
extern "C" void kernel_launch(void* const* d_in, const int* in_sizes, int n_in,
                              void* d_out, int out_size, void* d_ws, size_t ws_size,
                              hipStream_t stream) {
  const float* x  = (const float*)d_in[0];
  const float* Wq = (const float*)d_in[1];
  const float* bq = (const float*)d_in[2];
  const float* Wk = (const float*)d_in[3];
  const float* bk = (const float*)d_in[4];
  const float* Wv = (const float*)d_in[5];
  const float* bv = (const float*)d_in[6];
  const float* Ww = (const float*)d_in[7];
  const float* bw = (const float*)d_in[8];
  float* out = (float*)d_out;

  float* ws = (float*)d_ws;
  float* Mt   = ws;            // 4*4160 = 16640 floats
  float* Gred = ws + 16640;    // 16640 floats
  float* part = ws + 33280;    // 4*NPB*4160 floats (~8.5 MB)

  k_gram   <<<dim3(4 * NPB), 256, 0, stream>>>(x, part);
  k_reduce <<<dim3(65),      256, 0, stream>>>(part, Gred);
  k_combine<<<dim3(4),       256, 0, stream>>>(Gred, Wq, bq, Wk, bk,
                                               Wv, bv, Ww, bw, Mt);
  k_out    <<<dim3(256),     256, 0, stream>>>(x, Mt, out);
}

// Round 7
// 73.102 us; speedup vs baseline: 1.1841x; 1.1841x over previous
//
#include <hip/hip_runtime.h>
#include <stdint.h>

typedef unsigned int u32;
typedef unsigned short u16;
typedef short short8 __attribute__((ext_vector_type(8)));
typedef float f32x16 __attribute__((ext_vector_type(16)));

#define BN 8192
#define NPB 128           // partial blocks per batch (1 tile of 64 rows each)

__device__ __forceinline__ u32 f2b_u(float f){
  u32 x = __float_as_uint(f);
  return (x + 0x7fffu + ((x >> 16) & 1u)) >> 16;   // RNE f32->bf16
}
__device__ __forceinline__ float gelu_exact(float v){
  return 0.5f * v * (1.0f + erff(v * 0.70710678118654752440f));
}

// ---------------------------------------------------------------------------
// K1: per-block partial Gram via MFMA. One 64-row tile per block.
// grid = 4*NPB = 512 blocks (2/CU), 256 threads, single barrier.
// partial layout per block: 4096 floats G[i][j] + 64 floats m[j].
// ---------------------------------------------------------------------------
__global__ __launch_bounds__(256) void k_gram(const float* __restrict__ x,
                                              float* __restrict__ part){
  int bid = blockIdx.x;
  int b = bid >> 7, blk = bid & (NPB - 1);
  int t = threadIdx.x, w = t >> 6, lane = t & 63;
  const float* xb = x + (size_t)b * BN * 64 + (size_t)blk * 64 * 64;

  __shared__ __align__(16) u16 xT[64][72];     // [col][row] bf16, pad 72
  __shared__ float mred[256][16];

  int wi = w >> 1, wj = w & 1;                 // wave's G quadrant
  int r = t >> 2, cg = t & 3;                  // staging: row r, col-group cg

  // ---- stage 64 rows transposed bf16 + per-thread m partials ----
  const float4* src = (const float4*)(xb + (size_t)r * 64 + cg * 16);
  float4 v0 = src[0], v1 = src[1], v2 = src[2], v3 = src[3];
  float vv[16] = { v0.x, v0.y, v0.z, v0.w,  v1.x, v1.y, v1.z, v1.w,
                   v2.x, v2.y, v2.z, v2.w,  v3.x, v3.y, v3.z, v3.w };
  #pragma unroll
  for (int j = 0; j < 16; ++j){
    mred[t][j] = vv[j];
    xT[cg * 16 + j][r] = (u16)f2b_u(vv[j]);
  }
  __syncthreads();

  // ---- MFMA: 4 K-steps of 16 ----
  f32x16 acc;
  #pragma unroll
  for (int i = 0; i < 16; ++i) acc[i] = 0.f;
  #pragma unroll
  for (int ks = 0; ks < 4; ++ks){
    int n0 = ks * 16 + (lane >> 5) * 8;
    short8 af = *(const short8*)&xT[wi * 32 + (lane & 31)][n0];
    short8 bf = *(const short8*)&xT[wj * 32 + (lane & 31)][n0];
    acc = __builtin_amdgcn_mfma_f32_32x32x16_bf16(af, bf, acc, 0, 0, 0);
  }

  // ---- write G partial: C/D map col=lane&31, row=(reg&3)+8*(reg>>2)+4*(lane>>5)
  float* dst = part + (size_t)bid * 4160;
  #pragma unroll
  for (int rr = 0; rr < 16; ++rr){
    int grow = wi * 32 + (rr & 3) + 8 * (rr >> 2) + 4 * (lane >> 5);
    int gcol = wj * 32 + (lane & 31);
    dst[grow * 64 + gcol] = acc[rr];
  }

  // ---- m border: sum mred over the 64 rows (threads with same cg) ----
  if (t < 64){
    int cgc = t >> 4, j = t & 15;
    float s0 = 0.f, s1 = 0.f, s2 = 0.f, s3 = 0.f;
    for (int ss = 0; ss < 64; ss += 4){
      s0 += mred[cgc + 4 * ss][j];
      s1 += mred[cgc + 4 * (ss + 1)][j];
      s2 += mred[cgc + 4 * (ss + 2)][j];
      s3 += mred[cgc + 4 * (ss + 3)][j];
    }
    dst[4096 + t] = (s0 + s1) + (s2 + s3);
  }
}

// ---------------------------------------------------------------------------
// K2: stage-A reduction: 128 partials -> 8 group-partials.
// grid = 8 groups x 65 chunks = 520 blocks, 256 threads.
// element e in [0,16640): b = e/4160, idx = e%4160.
// part2[g][e] = sum_{p in g*16..+16} part[b][p][idx]. Coalesced over idx.
// ---------------------------------------------------------------------------
__global__ __launch_bounds__(256) void k_reduceA(const float* __restrict__ part,
                                                 float* __restrict__ part2){
  int g = blockIdx.x / 65, c = blockIdx.x - g * 65;
  int e = c * 256 + threadIdx.x;               // [0, 16640)
  int b = e / 4160, idx = e - b * 4160;
  const float* pb = part + ((size_t)b * NPB + g * 16) * 4160 + idx;
  float s0 = 0.f, s1 = 0.f, s2 = 0.f, s3 = 0.f;
  #pragma unroll
  for (int p = 0; p < 16; p += 4){
    s0 += pb[(size_t)p * 4160];
    s1 += pb[(size_t)(p + 1) * 4160];
    s2 += pb[(size_t)(p + 2) * 4160];
    s3 += pb[(size_t)(p + 3) * 4160];
  }
  part2[(size_t)g * 16640 + e] = (s0 + s1) + (s2 + s3);
}

// ---------------------------------------------------------------------------
// K3: per-batch combine. grid = 4 blocks, 512 threads (8 waves, 8 rows/wave).
// Prologue folds the final 8-way group sum into the Gt load.
//   T  = W~k G~          (64 x 65)
//   S  = T W~v^T         (64 x 64) stored transposed: St[j][i] = S[i][j]
//   M~ = W~w + INV8N * (S contracted with W~q)  (64 x 65, col 64 = const)
// ---------------------------------------------------------------------------
__global__ __launch_bounds__(512) void k_combine(
    const float* __restrict__ part2,
    const float* __restrict__ Wq, const float* __restrict__ bq,
    const float* __restrict__ Wk, const float* __restrict__ bk,
    const float* __restrict__ Wv, const float* __restrict__ bv,
    const float* __restrict__ Ww, const float* __restrict__ bw,
    float* __restrict__ Mt){
  int b = blockIdx.x;
  int t = threadIdx.x, w = t >> 6, lane = t & 63;

  __shared__ __align__(16) float Gt[65 * 68];
  __shared__ __align__(16) float Tl[64 * 68];
  __shared__ __align__(16) float St[64 * 68];

  const float* Gb = part2 + (size_t)b * 4160;
  for (int idx = t; idx < 4096; idx += 512){
    float s0 = 0.f, s1 = 0.f, s2 = 0.f, s3 = 0.f;
    #pragma unroll
    for (int g = 0; g < 8; g += 4){
      s0 += Gb[(size_t)g * 16640 + idx];
      s1 += Gb[(size_t)(g + 1) * 16640 + idx];
      s2 += Gb[(size_t)(g + 2) * 16640 + idx];
      s3 += Gb[(size_t)(g + 3) * 16640 + idx];
    }
    Gt[(idx >> 6) * 68 + (idx & 63)] = (s0 + s1) + (s2 + s3);
  }
  if (t < 64){
    float s = 0.f;
    #pragma unroll
    for (int g = 0; g < 8; ++g) s += Gb[(size_t)g * 16640 + 4096 + t];
    Gt[64 * 68 + t] = s;
    Gt[t * 68 + 64] = s;
  }
  if (t == 0) Gt[64 * 68 + 64] = (float)BN;
  __syncthreads();

  // ---- T[i][c] = sum_a W~k[i][a] G~[a][c], c = lane; rows i in [w*8,w*8+8) ----
  {
    float gcol[65];
    #pragma unroll
    for (int a = 0; a < 65; ++a) gcol[a] = Gt[a * 68 + lane];
    for (int i = w * 8; i < w * 8 + 8; ++i){
      float s0 = 0.f, s1 = 0.f, s2 = 0.f, s3 = 0.f;
      #pragma unroll
      for (int a = 0; a < 64; a += 4){
        s0 = fmaf(Wk[i * 64 + a],     gcol[a],     s0);
        s1 = fmaf(Wk[i * 64 + a + 1], gcol[a + 1], s1);
        s2 = fmaf(Wk[i * 64 + a + 2], gcol[a + 2], s2);
        s3 = fmaf(Wk[i * 64 + a + 3], gcol[a + 3], s3);
      }
      Tl[i * 68 + lane] = ((s0 + s1) + (s2 + s3)) + bk[i] * gcol[64];
    }
  }
  if (w == 0){   // column 64 of T, lane = i
    float s = 0.f;
    for (int a = 0; a < 64; ++a) s = fmaf(Wk[lane * 64 + a], Gt[a * 68 + 64], s);
    s = fmaf(bk[lane], (float)BN, s);
    Tl[lane * 68 + 64] = s;
  }
  __syncthreads();

  // ---- St[j][i] = S[i][j] = sum_c T[i][c] W~v[j][c], j = lane ----
  {
    float wv[65];
    const float4* Wv4 = (const float4*)(Wv + (size_t)lane * 64);
    #pragma unroll
    for (int c4 = 0; c4 < 16; ++c4){
      float4 vv = Wv4[c4];
      wv[4*c4] = vv.x; wv[4*c4+1] = vv.y; wv[4*c4+2] = vv.z; wv[4*c4+3] = vv.w;
    }
    wv[64] = bv[lane];
    for (int i = w * 8; i < w * 8 + 8; ++i){
      const float4* Tr = (const float4*)&Tl[i * 68];
      float s0 = 0.f, s1 = 0.f, s2 = 0.f, s3 = 0.f;
      #pragma unroll
      for (int cc = 0; cc < 16; ++cc){
        float4 tv = Tr[cc];
        s0 = fmaf(tv.x, wv[4*cc],     s0);
        s1 = fmaf(tv.y, wv[4*cc + 1], s1);
        s2 = fmaf(tv.z, wv[4*cc + 2], s2);
        s3 = fmaf(tv.w, wv[4*cc + 3], s3);
      }
      St[lane * 68 + i] = ((s0 + s1) + (s2 + s3)) + Tl[i * 68 + 64] * wv[64];
    }
  }
  __syncthreads();

  // ---- M~[d][c] = W~w[d][c] + INV8N * sum_e S[e][d] W~q[e][c] ----
  {
    const float inv = 1.0f / 65536.0f;   // 1/(sqrt(64)*8192)
    float wq[64];
    #pragma unroll
    for (int i = 0; i < 64; ++i) wq[i] = Wq[i * 64 + lane];   // column c = lane
    float* Mb = Mt + (size_t)b * 4160;
    for (int d = w * 8; d < w * 8 + 8; ++d){
      const float4* Sr = (const float4*)&St[d * 68];
      float s0 = 0.f, s1 = 0.f, s2 = 0.f, s3 = 0.f;
      #pragma unroll
      for (int ii = 0; ii < 16; ++ii){
        float4 sv = Sr[ii];
        s0 = fmaf(sv.x, wq[4*ii],     s0);
        s1 = fmaf(sv.y, wq[4*ii + 1], s1);
        s2 = fmaf(sv.z, wq[4*ii + 2], s2);
        s3 = fmaf(sv.w, wq[4*ii + 3], s3);
      }
      Mb[d * 65 + lane] = fmaf(inv, (s0 + s1) + (s2 + s3), Ww[d * 64 + lane]);
    }
    if (w == 0){   // affine-const column, lane = d
      float s = 0.f;
      for (int i = 0; i < 64; ++i) s = fmaf(St[lane * 68 + i], bq[i], s);
      Mb[lane * 65 + 64] = fmaf(inv, s, bw[lane]);
    }
  }
}

// ---------------------------------------------------------------------------
// K4: out_n = gelu(M~ x~_n), FP32 out. grid = 256 blocks (64/batch).
// Wave w: h=w&1 row-half (lane = row), dh=w>>1 channel-half (32 ch).
// LDS float2 transpose -> coalesced 128B row-segment stores.
// ---------------------------------------------------------------------------
__global__ __launch_bounds__(256) void k_out(const float* __restrict__ x,
                                             const float* __restrict__ Mt,
                                             float* __restrict__ out){
  int bid = blockIdx.x;
  int b = bid >> 6, blk = bid & 63;
  int t = threadIdx.x, w = t >> 6, lane = t & 63;
  int h = w & 1, dh = w >> 1;
  int r0 = blk * 128 + h * 64;
  int row = r0 + lane;

  const float4* xr4 = (const float4*)(x + ((size_t)(b * BN + row)) * 64);
  float xv[64];
  #pragma unroll
  for (int q = 0; q < 16; ++q){
    float4 u = xr4[q];
    xv[4*q] = u.x; xv[4*q+1] = u.y; xv[4*q+2] = u.z; xv[4*q+3] = u.w;
  }

  __shared__ __align__(16) float tp[4][64 * 34];
  float* tpw = &tp[w][0];
  const float* Mb = Mt + (size_t)b * 4160;

  #pragma unroll 1
  for (int dd = 0; dd < 16; ++dd){
    int d0 = dh * 32 + 2 * dd, d1 = d0 + 1;
    float a0 = Mb[d0 * 65 + 64];      // affine const (uniform -> s_load)
    float a1 = Mb[d1 * 65 + 64];
    #pragma unroll
    for (int c = 0; c < 64; ++c){
      a0 = fmaf(Mb[d0 * 65 + c], xv[c], a0);
      a1 = fmaf(Mb[d1 * 65 + c], xv[c], a1);
    }
    a0 = gelu_exact(a0);
    a1 = gelu_exact(a1);
    *(float2*)&tpw[lane * 34 + 2 * dd] = make_float2(a0, a1);
  }
  __syncthreads();

  // store: 4 rows per iter, 16 lanes cover one 32-float (128B) row segment
  #pragma unroll 1
  for (int rr = 0; rr < 16; ++rr){
    int rloc = rr * 4 + (lane >> 4);
    int p = lane & 15;
    float2 v = *(const float2*)&tpw[rloc * 34 + 2 * p];
    float* dst = out + ((size_t)(b * BN + r0 + rloc)) * 64 + dh * 32 + 2 * p;
    *(float2*)dst = v;
  }
}

// ---------------------------------------------------------------------------
extern "C" void kernel_launch(void* const* d_in, const int* in_sizes, int n_in,
                              void* d_out, int out_size, void* d_ws, size_t ws_size,
                              hipStream_t stream) {
  const float* x  = (const float*)d_in[0];
  const float* Wq = (const float*)d_in[1];
  const float* bq = (const float*)d_in[2];
  const float* Wk = (const float*)d_in[3];
  const float* bk = (const float*)d_in[4];
  const float* Wv = (const float*)d_in[5];
  const float* bv = (const float*)d_in[6];
  const float* Ww = (const float*)d_in[7];
  const float* bw = (const float*)d_in[8];
  float* out = (float*)d_out;

  float* ws = (float*)d_ws;
  float* Mt    = ws;             // 4*4160 = 16640 floats
  float* part2 = ws + 16640;     // 8*16640 = 133120 floats
  float* part  = ws + 149760;    // 4*NPB*4160 floats (~8.5 MB)

  k_gram   <<<dim3(4 * NPB), 256, 0, stream>>>(x, part);
  k_reduceA<<<dim3(520),     256, 0, stream>>>(part, part2);
  k_combine<<<dim3(4),       512, 0, stream>>>(part2, Wq, bq, Wk, bk,
                                               Wv, bv, Ww, bw, Mt);
  k_out    <<<dim3(256),     256, 0, stream>>>(x, Mt, out);
}